// Round 12
// baseline (91.872 us; speedup 1.0000x reference)
//
#include <hip/hip_runtime.h>

#define HH 256
#define WW 256
#define ZZ 256
#define BBH 512                           // B*H lines
#define LSTRIDE (WW * ZZ)                 // floats between h-lines
#define NROWS (BBH * WW)                  // 131072
#define NELEM ((long long)NROWS * ZZ)     // 33554432

#define SEGW 8
#define NTW (WW / SEGW)                   // 32 w-tiles
#define NPAIR (BBH / 2)                   // 256 line pairs
#define NSEG (NPAIR * NTW)                // 8192 wave segments
#define WPB 4
#define NTASK (NSEG / WPB)                // 2048 block-tasks
#define GRIDP 1280                        // persistent blocks = 5/CU residency

typedef float vf4 __attribute__((ext_vector_type(4)));

__device__ __forceinline__ vf4 ld4(const float* p) { return *(const vf4*)p; }
__device__ __forceinline__ vf4 ldnt4(const float* p) {
    return __builtin_nontemporal_load((const vf4*)p);
}

// aligned store of one output row at d_out+1: lane j stores slot j+1 =
// {own o.w, next-lane o.x,o.y,o.z}; edges scalar. rowp = outD + r*ZZ.
__device__ __forceinline__ void store_row(float* rowp, vf4 o, int lane) {
    const float nx = __shfl_down(o.x, 1);
    const float ny = __shfl_down(o.y, 1);
    const float nz = __shfl_down(o.z, 1);
    if (lane < 63) {
        vf4 st = {o.w, nx, ny, nz};
        __builtin_nontemporal_store(st, (vf4*)(rowp + 4 * (lane + 1)));
    }
    if (lane == 0) {
        __builtin_nontemporal_store(o.x, rowp + 1);
        __builtin_nontemporal_store(o.y, rowp + 2);
        __builtin_nontemporal_store(o.z, rowp + 3);
    }
    if (lane == 63) __builtin_nontemporal_store(o.w, rowp + ZZ);
}

// d_ws layout: uint ctr @0 (zeroed each launch); pad to 256B;
//              float part_sum[NSEG]; float part_max[NSEG]  (64 KB)
__global__ __launch_bounds__(256) void stencil7_kernel(
    const float* __restrict__ x, const float* __restrict__ coeff,
    const float* __restrict__ ref, float* __restrict__ outD,
    unsigned int* __restrict__ ctr,
    float* __restrict__ part_sum, float* __restrict__ part_max)
{
    __shared__ int s_task;
    const int tid  = threadIdx.x;
    const int k    = tid >> 6;
    const int lane = tid & 63;
    const int lo   = lane << 2;
    const vf4 z4 = {0.f, 0.f, 0.f, 0.f};

    int task = blockIdx.x;                // static first task
    while (task < NTASK) {
        const int seg  = __builtin_amdgcn_readfirstlane(task * WPB + k);
        const int p    = seg >> 5;            // line-pair id
        const int wt   = seg & (NTW - 1);     // w-tile id
        const int bh0  = p * 2;               // even line
        const int w0   = wt * SEGW;
        const int h0   = bh0 & (HH - 1);
        const bool hasS = (h0 > 0);
        const bool hasN = (h0 != HH - 2);
        const long long SOFF = hasS ? -(long long)LSTRIDE : 0;
        const long long NOFF = hasN ? 2LL * LSTRIDE : (long long)LSTRIDE;

        const float* px0  = x   + (long long)(bh0 * WW + w0) * ZZ + lo;
        const float* px1  = px0 + LSTRIDE;
        const float* prf0 = ref + (long long)(bh0 * WW + w0) * ZZ + lo;
        const float* prf1 = prf0 + LSTRIDE;
        const float* pc0  = coeff + 7LL * (bh0 * WW + w0);
        const float* pc1  = pc0 + 7 * WW;
        float* prow0 = outD + (long long)(bh0 * WW + w0) * ZZ;
        float* prow1 = prow0 + LSTRIDE;

        // ---- prologue ----
        vf4 cw0, cw1;
        if (w0 > 0) { cw0 = ld4(px0 - ZZ); cw1 = ld4(px1 - ZZ); }
        else        { cw0 = z4;            cw1 = z4; }
        vf4 c00 = ld4(px0);           vf4 c10 = ld4(px1);
        vf4 c01 = ld4(px0 + ZZ);      vf4 c11 = ld4(px1 + ZZ);
        vf4 sC  = ld4(px0 + SOFF);    vf4 nC  = ld4(px0 + NOFF);
        vf4 rf0 = ldnt4(prf0);        vf4 rf1 = ldnt4(prf1);
        float k0 = pc0[0], k1 = pc0[1], k2 = hasS ? pc0[2] : 0.f, k3 = pc0[3],
              k4 = pc0[4], k5 = pc0[5], k6 = pc0[6];
        float j0 = pc1[0], j1 = pc1[1], j2 = pc1[2], j3 = hasN ? pc1[3] : 0.f,
              j4 = pc1[4], j5 = pc1[5], j6 = pc1[6];

        float acc_s = 0.f, acc_m = 0.f;

        #pragma unroll
        for (int i = 0; i < SEGW - 1; ++i) {
            // ---- prefetch for step i+1 ----
            int ce = w0 + i + 2; if (ce > WW - 1) ce = WW - 1;
            const long long ceo = (long long)(ce - w0) * ZZ;
            vf4 c0n = ld4(px0 + ceo);
            vf4 c1n = ld4(px1 + ceo);
            const long long r1o = (long long)(i + 1) * ZZ;
            vf4 sN  = ld4(px0 + r1o + SOFF);
            vf4 nN  = ld4(px0 + r1o + NOFF);
            vf4 rf0n = ldnt4(prf0 + r1o);
            vf4 rf1n = ldnt4(prf1 + r1o);
            const float* qc0 = pc0 + 7 * (i + 1);
            const float* qc1 = pc1 + 7 * (i + 1);
            const float m0 = qc0[0], m1 = qc0[1], m2 = hasS ? qc0[2] : 0.f,
                        m3 = qc0[3], m4 = qc0[4], m5 = qc0[5], m6 = qc0[6];
            const float n0 = qc1[0], n1 = qc1[1], n2 = qc1[2],
                        n3 = hasN ? qc1[3] : 0.f, n4 = qc1[4], n5 = qc1[5], n6 = qc1[6];

            // ---- compute row0 (line bh0): S=sC, N=c10 ----
            {
                float bm1 = __shfl_up(c00.w, 1);
                if (lane == 0) bm1 = 0.f;
                float tp1 = __shfl_down(c00.x, 1);
                if (lane == 63) tp1 = 0.f;
                const vf4 bot = {bm1, c00.x, c00.y, c00.z};
                const vf4 top = {c00.y, c00.z, c00.w, tp1};
                const vf4 o = k0*cw0 + k1*c01 + k2*sC + k3*c10 + k4*bot + k5*top + k6*c00;
                store_row(prow0 + (long long)i * ZZ, o, lane);
                const vf4 e = o - rf0;
                acc_s += e.x*e.x + e.y*e.y + e.z*e.z + e.w*e.w;
                acc_m  = fmaxf(acc_m, fmaxf(fmaxf(fabsf(e.x), fabsf(e.y)),
                                            fmaxf(fabsf(e.z), fabsf(e.w))));
            }
            // ---- compute row1 (line bh0+1): S=c00, N=nC ----
            {
                float bm1 = __shfl_up(c10.w, 1);
                if (lane == 0) bm1 = 0.f;
                float tp1 = __shfl_down(c10.x, 1);
                if (lane == 63) tp1 = 0.f;
                const vf4 bot = {bm1, c10.x, c10.y, c10.z};
                const vf4 top = {c10.y, c10.z, c10.w, tp1};
                const vf4 o = j0*cw1 + j1*c11 + j2*c00 + j3*nC + j4*bot + j5*top + j6*c10;
                store_row(prow1 + (long long)i * ZZ, o, lane);
                const vf4 e = o - rf1;
                acc_s += e.x*e.x + e.y*e.y + e.z*e.z + e.w*e.w;
                acc_m  = fmaxf(acc_m, fmaxf(fmaxf(fabsf(e.x), fabsf(e.y)),
                                            fmaxf(fabsf(e.z), fabsf(e.w))));
            }

            // ---- rotate ----
            cw0 = c00; c00 = c01; c01 = c0n;
            cw1 = c10; c10 = c11; c11 = c1n;
            sC = sN; nC = nN; rf0 = rf0n; rf1 = rf1n;
            k0 = m0; k1 = m1; k2 = m2; k3 = m3; k4 = m4; k5 = m5; k6 = m6;
            j0 = n0; j1 = n1; j2 = n2; j3 = n3; j4 = n4; j5 = n5; j6 = n6;
        }

        // ---- peeled last step ----
        {
            const int i = SEGW - 1;
            if (w0 + i == WW - 1) { k1 = 0.f; j1 = 0.f; }
            {
                float bm1 = __shfl_up(c00.w, 1);
                if (lane == 0) bm1 = 0.f;
                float tp1 = __shfl_down(c00.x, 1);
                if (lane == 63) tp1 = 0.f;
                const vf4 bot = {bm1, c00.x, c00.y, c00.z};
                const vf4 top = {c00.y, c00.z, c00.w, tp1};
                const vf4 o = k0*cw0 + k1*c01 + k2*sC + k3*c10 + k4*bot + k5*top + k6*c00;
                store_row(prow0 + (long long)i * ZZ, o, lane);
                const vf4 e = o - rf0;
                acc_s += e.x*e.x + e.y*e.y + e.z*e.z + e.w*e.w;
                acc_m  = fmaxf(acc_m, fmaxf(fmaxf(fabsf(e.x), fabsf(e.y)),
                                            fmaxf(fabsf(e.z), fabsf(e.w))));
            }
            {
                float bm1 = __shfl_up(c10.w, 1);
                if (lane == 0) bm1 = 0.f;
                float tp1 = __shfl_down(c10.x, 1);
                if (lane == 63) tp1 = 0.f;
                const vf4 bot = {bm1, c10.x, c10.y, c10.z};
                const vf4 top = {c10.y, c10.z, c10.w, tp1};
                const vf4 o = j0*cw1 + j1*c11 + j2*c00 + j3*nC + j4*bot + j5*top + j6*c10;
                store_row(prow1 + (long long)i * ZZ, o, lane);
                const vf4 e = o - rf1;
                acc_s += e.x*e.x + e.y*e.y + e.z*e.z + e.w*e.w;
                acc_m  = fmaxf(acc_m, fmaxf(fmaxf(fabsf(e.x), fabsf(e.y)),
                                            fmaxf(fabsf(e.z), fabsf(e.w))));
            }
        }

        // ---- per-segment partials (deterministic: one writer per seg) ----
        #pragma unroll
        for (int off = 32; off > 0; off >>= 1) {
            acc_s += __shfl_down(acc_s, off);
            acc_m  = fmaxf(acc_m, __shfl_down(acc_m, off));
        }
        if (lane == 0) { part_sum[seg] = acc_s; part_max[seg] = acc_m; }

        // ---- grab next task ----
        __syncthreads();                 // all waves done reading s_task
        if (tid == 0) s_task = GRIDP + (int)atomicAdd(ctr, 1u);
        __syncthreads();
        task = s_task;
    }
}

__global__ __launch_bounds__(256) void finalize_kernel(
    const float* __restrict__ part_sum, const float* __restrict__ part_max,
    float* __restrict__ loss_out, float* __restrict__ amax_out)
{
    const int tid  = threadIdx.x;
    const int wave = tid >> 6;
    const int lane = tid & 63;

    double s = 0.0;
    float  m = 0.f;
    for (int i = tid; i < NSEG; i += 256) {
        s += (double)part_sum[i];
        m  = fmaxf(m, part_max[i]);
    }
    #pragma unroll
    for (int off = 32; off > 0; off >>= 1) {
        s += __shfl_down(s, off);
        m  = fmaxf(m, __shfl_down(m, off));
    }
    __shared__ double ds[4];
    __shared__ float  dm[4];
    if (lane == 0) { ds[wave] = s; dm[wave] = m; }
    __syncthreads();
    if (tid == 0) {
        const double S = ds[0] + ds[1] + ds[2] + ds[3];
        const float  M = fmaxf(fmaxf(dm[0], dm[1]), fmaxf(dm[2], dm[3]));
        *loss_out = (float)(S / (double)NELEM);
        *amax_out = M;
    }
}

extern "C" void kernel_launch(void* const* d_in, const int* in_sizes, int n_in,
                              void* d_out, int out_size, void* d_ws, size_t ws_size,
                              hipStream_t stream) {
    const float* x     = (const float*)d_in[0];
    const float* coeff = (const float*)d_in[1];
    const float* ref   = (const float*)d_in[2];

    float* outf = (float*)d_out;
    float* loss_out = outf;               // d_out[0]
    float* amax_out = outf + 1 + NELEM;   // d_out[N+1]

    unsigned int* ctr = (unsigned int*)d_ws;
    float* part_sum = (float*)((char*)d_ws + 256);
    float* part_max = part_sum + NSEG;

    hipMemsetAsync(ctr, 0, 4, stream);

    stencil7_kernel<<<dim3(GRIDP), dim3(256), 0, stream>>>(
        x, coeff, ref, outf, ctr, part_sum, part_max);
    finalize_kernel<<<dim3(1), dim3(256), 0, stream>>>(
        part_sum, part_max, loss_out, amax_out);
}

// Round 13
// 88.689 us; speedup vs baseline: 1.0359x; 1.0359x over previous
//
#include <hip/hip_runtime.h>

#define HH 256
#define WW 256
#define ZZ 256
#define BBH 512                           // B*H lines
#define LSTRIDE (WW * ZZ)                 // floats between h-lines
#define NROWS (BBH * WW)                  // 131072
#define NELEM ((long long)NROWS * ZZ)     // 33554432

#define SEGW 8
#define NTW (WW / SEGW)                   // 32 w-tiles
#define NPAIR (BBH / 2)                   // 256 line pairs
#define NSEG (NPAIR * NTW)                // 8192 wave segments
#define WPB 4
#define NBLK (NSEG / WPB)                 // 2048 blocks
#define NXCD 8
#define CPX (NBLK / NXCD)                 // 256 blocks per XCD slab

typedef float vf4 __attribute__((ext_vector_type(4)));

__device__ __forceinline__ vf4 ld4(const float* p) { return *(const vf4*)p; }
__device__ __forceinline__ vf4 ldnt4(const float* p) {
    return __builtin_nontemporal_load((const vf4*)p);
}

// aligned store of one output row at d_out+1: lane j stores slot j+1 =
// {own o.w, next-lane o.x,o.y,o.z}; edges scalar. rowp = outD + r*ZZ.
__device__ __forceinline__ void store_row(float* rowp, vf4 o, int lane) {
    const float nx = __shfl_down(o.x, 1);
    const float ny = __shfl_down(o.y, 1);
    const float nz = __shfl_down(o.z, 1);
    if (lane < 63) {
        vf4 st = {o.w, nx, ny, nz};
        __builtin_nontemporal_store(st, (vf4*)(rowp + 4 * (lane + 1)));
    }
    if (lane == 0) {
        __builtin_nontemporal_store(o.x, rowp + 1);
        __builtin_nontemporal_store(o.y, rowp + 2);
        __builtin_nontemporal_store(o.z, rowp + 3);
    }
    if (lane == 63) __builtin_nontemporal_store(o.w, rowp + ZZ);
}

// d_ws layout: float part_sum[NBLK]; float part_max[NBLK]
__global__ __launch_bounds__(256) void stencil7_kernel(
    const float* __restrict__ x, const float* __restrict__ coeff,
    const float* __restrict__ ref, float* __restrict__ outD,
    float* __restrict__ part_sum, float* __restrict__ part_max)
{
    const int tid  = threadIdx.x;
    const int k    = tid >> 6;
    const int lane = tid & 63;
    const int b    = blockIdx.x;
    // XCD-slab swizzle: each XCD gets 256 consecutive sb -> 64 contiguous lines
    const int sb   = (b & (NXCD - 1)) * CPX + (b >> 3);
    const int seg  = __builtin_amdgcn_readfirstlane(sb * WPB + k);
    const int p    = seg >> 5;            // line-pair id
    const int wt   = seg & (NTW - 1);     // w-tile id
    const int bh0  = p * 2;               // even line
    const int w0   = wt * SEGW;
    const int h0   = bh0 & (HH - 1);
    const bool hasS = (h0 > 0);           // row0 south exists
    const bool hasN = (h0 != HH - 2);     // row1 north exists
    const long long SOFF = hasS ? -(long long)LSTRIDE : 0;
    const long long NOFF = hasN ? 2LL * LSTRIDE : (long long)LSTRIDE;
    const int lo = lane << 2;

    const float* px0  = x   + (long long)(bh0 * WW + w0) * ZZ + lo;
    const float* px1  = px0 + LSTRIDE;
    const float* prf0 = ref + (long long)(bh0 * WW + w0) * ZZ + lo;
    const float* prf1 = prf0 + LSTRIDE;
    const float* pc0  = coeff + 7LL * (bh0 * WW + w0);
    const float* pc1  = pc0 + 7 * WW;
    float* prow0 = outD + (long long)(bh0 * WW + w0) * ZZ;
    float* prow1 = prow0 + LSTRIDE;

    const vf4 z4 = {0.f, 0.f, 0.f, 0.f};

    // ---- prologue: center ring W,C,E,F and depth-2 groups A(i=0), B(i=1) ----
    vf4 W0, W1;
    if (w0 > 0) { W0 = ld4(px0 - ZZ); W1 = ld4(px1 - ZZ); }
    else        { W0 = z4;            W1 = z4; }
    vf4 C0 = ld4(px0);            vf4 C1 = ld4(px1);
    vf4 E0 = ld4(px0 + ZZ);       vf4 E1 = ld4(px1 + ZZ);
    vf4 F0 = ld4(px0 + 2 * ZZ);   vf4 F1 = ld4(px1 + 2 * ZZ);
    vf4 sA = ld4(px0 + SOFF);     vf4 nA = ld4(px0 + NOFF);
    vf4 sB = ld4(px0 + ZZ + SOFF); vf4 nB = ld4(px0 + ZZ + NOFF);
    vf4 rA0 = ldnt4(prf0);        vf4 rA1 = ldnt4(prf1);
    vf4 rB0 = ldnt4(prf0 + ZZ);   vf4 rB1 = ldnt4(prf1 + ZZ);
    float kA0 = pc0[0], kA1 = pc0[1], kA2 = hasS ? pc0[2] : 0.f, kA3 = pc0[3],
          kA4 = pc0[4], kA5 = pc0[5], kA6 = pc0[6];
    float jA0 = pc1[0], jA1 = pc1[1], jA2 = pc1[2], jA3 = hasN ? pc1[3] : 0.f,
          jA4 = pc1[4], jA5 = pc1[5], jA6 = pc1[6];
    float kB0 = pc0[7], kB1 = pc0[8], kB2 = hasS ? pc0[9] : 0.f, kB3 = pc0[10],
          kB4 = pc0[11], kB5 = pc0[12], kB6 = pc0[13];
    float jB0 = pc1[7], jB1 = pc1[8], jB2 = pc1[9], jB3 = hasN ? pc1[10] : 0.f,
          jB4 = pc1[11], jB5 = pc1[12], jB6 = pc1[13];

    float acc_s = 0.f, acc_m = 0.f;

    #pragma unroll
    for (int i = 0; i < SEGW; ++i) {
        // ---- issue prefetches (guards fold at compile time) ----
        vf4 sT = z4, nT = z4, rT0 = z4, rT1 = z4;
        float kT0 = 0.f, kT1 = 0.f, kT2 = 0.f, kT3 = 0.f, kT4 = 0.f, kT5 = 0.f, kT6 = 0.f;
        float jT0 = 0.f, jT1 = 0.f, jT2 = 0.f, jT3 = 0.f, jT4 = 0.f, jT5 = 0.f, jT6 = 0.f;
        if (i + 2 < SEGW) {                     // group for step i+2
            const long long go = (long long)(i + 2) * ZZ;
            sT  = ld4(px0 + go + SOFF);
            nT  = ld4(px0 + go + NOFF);
            rT0 = ldnt4(prf0 + go);
            rT1 = ldnt4(prf1 + go);
            const float* qc0 = pc0 + 7 * (i + 2);
            const float* qc1 = pc1 + 7 * (i + 2);
            kT0 = qc0[0]; kT1 = qc0[1]; kT2 = hasS ? qc0[2] : 0.f; kT3 = qc0[3];
            kT4 = qc0[4]; kT5 = qc0[5]; kT6 = qc0[6];
            jT0 = qc1[0]; jT1 = qc1[1]; jT2 = qc1[2]; jT3 = hasN ? qc1[3] : 0.f;
            jT4 = qc1[4]; jT5 = qc1[5]; jT6 = qc1[6];
        }
        vf4 nF0 = z4, nF1 = z4;
        if (i <= SEGW - 3) {                    // center x[i+3] (east of step i+2)
            int wf = w0 + i + 3; if (wf > WW - 1) wf = WW - 1;
            const long long fo = (long long)(wf - w0) * ZZ;
            nF0 = ld4(px0 + fo);
            nF1 = ld4(px1 + fo);
        }

        // global east edge: zero east coeff (only possible at last step)
        if (i == SEGW - 1) {
            if (w0 + i == WW - 1) { kA1 = 0.f; jA1 = 0.f; }
        }

        // ---- compute row0 (line bh0): W0,C0,E0; S=sA, N=C1 ----
        {
            float bm1 = __shfl_up(C0.w, 1);
            if (lane == 0) bm1 = 0.f;
            float tp1 = __shfl_down(C0.x, 1);
            if (lane == 63) tp1 = 0.f;
            const vf4 bot = {bm1, C0.x, C0.y, C0.z};
            const vf4 top = {C0.y, C0.z, C0.w, tp1};
            const vf4 o = kA0*W0 + kA1*E0 + kA2*sA + kA3*C1 + kA4*bot + kA5*top + kA6*C0;
            store_row(prow0 + (long long)i * ZZ, o, lane);
            const vf4 e = o - rA0;
            acc_s += e.x*e.x + e.y*e.y + e.z*e.z + e.w*e.w;
            acc_m  = fmaxf(acc_m, fmaxf(fmaxf(fabsf(e.x), fabsf(e.y)),
                                        fmaxf(fabsf(e.z), fabsf(e.w))));
        }
        // ---- compute row1 (line bh0+1): W1,C1,E1; S=C0, N=nA ----
        {
            float bm1 = __shfl_up(C1.w, 1);
            if (lane == 0) bm1 = 0.f;
            float tp1 = __shfl_down(C1.x, 1);
            if (lane == 63) tp1 = 0.f;
            const vf4 bot = {bm1, C1.x, C1.y, C1.z};
            const vf4 top = {C1.y, C1.z, C1.w, tp1};
            const vf4 o = jA0*W1 + jA1*E1 + jA2*C0 + jA3*nA + jA4*bot + jA5*top + jA6*C1;
            store_row(prow1 + (long long)i * ZZ, o, lane);
            const vf4 e = o - rA1;
            acc_s += e.x*e.x + e.y*e.y + e.z*e.z + e.w*e.w;
            acc_m  = fmaxf(acc_m, fmaxf(fmaxf(fabsf(e.x), fabsf(e.y)),
                                        fmaxf(fabsf(e.z), fabsf(e.w))));
        }

        // ---- rotate pipeline ----
        W0 = C0; C0 = E0; E0 = F0;
        W1 = C1; C1 = E1; E1 = F1;
        if (i <= SEGW - 3) { F0 = nF0; F1 = nF1; }
        sA = sB; nA = nB; rA0 = rB0; rA1 = rB1;
        kA0 = kB0; kA1 = kB1; kA2 = kB2; kA3 = kB3; kA4 = kB4; kA5 = kB5; kA6 = kB6;
        jA0 = jB0; jA1 = jB1; jA2 = jB2; jA3 = jB3; jA4 = jB4; jA5 = jB5; jA6 = jB6;
        if (i + 2 < SEGW) {
            sB = sT; nB = nT; rB0 = rT0; rB1 = rT1;
            kB0 = kT0; kB1 = kT1; kB2 = kT2; kB3 = kT3; kB4 = kT4; kB5 = kT5; kB6 = kT6;
            jB0 = jT0; jB1 = jT1; jB2 = jT2; jB3 = jT3; jB4 = jT4; jB5 = jT5; jB6 = jT6;
        }
    }

    // ---- wave + block reduction ----
    #pragma unroll
    for (int off = 32; off > 0; off >>= 1) {
        acc_s += __shfl_down(acc_s, off);
        acc_m  = fmaxf(acc_m, __shfl_down(acc_m, off));
    }
    __shared__ float ss[WPB];
    __shared__ float sm[WPB];
    if (lane == 0) { ss[k] = acc_s; sm[k] = acc_m; }
    __syncthreads();
    if (tid == 0) {
        part_sum[blockIdx.x] = ss[0] + ss[1] + ss[2] + ss[3];
        part_max[blockIdx.x] = fmaxf(fmaxf(sm[0], sm[1]), fmaxf(sm[2], sm[3]));
    }
}

__global__ __launch_bounds__(256) void finalize_kernel(
    const float* __restrict__ part_sum, const float* __restrict__ part_max,
    float* __restrict__ loss_out, float* __restrict__ amax_out)
{
    const int tid  = threadIdx.x;
    const int wave = tid >> 6;
    const int lane = tid & 63;

    double s = 0.0;
    float  m = 0.f;
    for (int i = tid; i < NBLK; i += 256) {
        s += (double)part_sum[i];
        m  = fmaxf(m, part_max[i]);
    }
    #pragma unroll
    for (int off = 32; off > 0; off >>= 1) {
        s += __shfl_down(s, off);
        m  = fmaxf(m, __shfl_down(m, off));
    }
    __shared__ double ds[4];
    __shared__ float  dm[4];
    if (lane == 0) { ds[wave] = s; dm[wave] = m; }
    __syncthreads();
    if (tid == 0) {
        const double S = ds[0] + ds[1] + ds[2] + ds[3];
        const float  M = fmaxf(fmaxf(dm[0], dm[1]), fmaxf(dm[2], dm[3]));
        *loss_out = (float)(S / (double)NELEM);
        *amax_out = M;
    }
}

extern "C" void kernel_launch(void* const* d_in, const int* in_sizes, int n_in,
                              void* d_out, int out_size, void* d_ws, size_t ws_size,
                              hipStream_t stream) {
    const float* x     = (const float*)d_in[0];
    const float* coeff = (const float*)d_in[1];
    const float* ref   = (const float*)d_in[2];

    float* outf = (float*)d_out;
    float* loss_out = outf;               // d_out[0]
    float* amax_out = outf + 1 + NELEM;   // d_out[N+1]

    float* part_sum = (float*)d_ws;
    float* part_max = part_sum + NBLK;

    stencil7_kernel<<<dim3(NBLK), dim3(256), 0, stream>>>(
        x, coeff, ref, outf, part_sum, part_max);
    finalize_kernel<<<dim3(1), dim3(256), 0, stream>>>(
        part_sum, part_max, loss_out, amax_out);
}